// Round 1
// baseline (720.087 us; speedup 1.0000x reference)
//
#include <hip/hip_runtime.h>
#include <math.h>

// ---------------------------------------------------------------------------
// HierarchicalTimeAttention on MI355X
//
// Algebraic plan (all fp32):
//   p    = nf @ (Wq@Wk^T) + bq@Wk^T          [N,128]  (so k-GEMM over E is gone)
//   qb_n = nf_n . (Wq bk) + bq.bk            [N]
//   attn_e = (t_e . p[src] + qb[src]) * SCALE ; ex = exp(attn)  (no max pass: |attn|<~4)
//   seg = assign*N + src ; denom[seg] += ex ; cnt[seg] += 1
//   scale_e = ex / (denom[seg]*cnt[seg])                    (1/nne folded at end)
//   agg[n] = sum_{e: src=n} scale_e * t_e ; sw[n] = sum scale_e  (via counting sort, no atomics)
//   out = relu( (agg @ (Wv@Wo) + sw * (bv@Wo)) * (1/nne) + bo )
// ---------------------------------------------------------------------------

#define NN 50000
#define NE 600000
#define DD 128
#define NC 8
#define SCALEF 0.08838834764831845f

// ---- workspace element offsets (fp32/int32 units) ----
// zeroed region:
#define OFF_DENOM    0          // 400000 f32
#define OFF_CNTSEG   400000     // 400000 i32
#define OFF_NODECNT  800000     // 50000 i32
#define OFF_FILL     850000     // 50000 i32
#define OFF_HIST     900000     // 8 i32 (pad to 16)
#define ZERO_ELEMS   900016
// non-zeroed (fully written each call):
#define OFF_NODEOFF  900016     // 50000 i32
#define OFF_PARTIAL  950016     // 256 i32
#define OFF_INVNNE   950272     // 1 f32
#define OFF_C0       950276     // 1 f32
#define OFF_BQK      950528     // 128 f32
#define OFF_BVO      950656     // 128 f32
#define OFF_WQBK     950784     // 128 f32
#define OFF_WQK      950912     // 16384 f32
#define OFF_WVO      967296     // 16384 f32
#define OFF_QB       983680     // 50000 f32
#define OFF_EX       1033680    // 600000 f32
#define OFF_ASSIGN   1633680    // 600000 i32
#define OFF_SORTED   2233680    // 600000 i32
#define OFF_SW       2833680    // 50000 f32
#define OFF_P        2883680    // 6400000 f32  (aliased: agg reuses this after pass1)
// total: 9,283,680 elems = ~37.1 MB

// --- tiny precompute: Wqk = Wq@Wk^T, Wvo = Wv@Wo, bqk, bvo, wqbk, c0 ---
__global__ __launch_bounds__(128) void k_pre(
    const float* __restrict__ Wq, const float* __restrict__ bq,
    const float* __restrict__ Wk, const float* __restrict__ bk,
    const float* __restrict__ Wv, const float* __restrict__ bv,
    const float* __restrict__ Wo,
    float* __restrict__ Wqk, float* __restrict__ bqk,
    float* __restrict__ Wvo, float* __restrict__ bvo,
    float* __restrict__ wqbk, float* __restrict__ c0) {
  __shared__ float rq[DD], rv[DD];
  int b = blockIdx.x, i = threadIdx.x;
  if (b < DD) {
    rq[i] = Wq[b * DD + i];
    rv[i] = Wv[b * DD + i];
    __syncthreads();
    float aq = 0.f, av = 0.f;
    for (int j = 0; j < DD; j++) {
      aq += rq[j] * Wk[i * DD + j];   // Wqk[b,i] = Wq row b . Wk row i
      av += rv[j] * Wo[j * DD + i];   // Wvo[b,i] = Wv row b . Wo col i
    }
    Wqk[b * DD + i] = aq;
    Wvo[b * DD + i] = av;
  } else {
    float a1 = 0.f, a2 = 0.f, a3 = 0.f;
    for (int j = 0; j < DD; j++) {
      a1 += bq[j] * Wk[i * DD + j];   // bqk[i]
      a2 += bv[j] * Wo[j * DD + i];   // bvo[i]
      a3 += Wq[i * DD + j] * bk[j];   // wqbk[i]
    }
    bqk[i] = a1; bvo[i] = a2; wqbk[i] = a3;
    if (i == 0) {
      float s = 0.f;
      for (int j = 0; j < DD; j++) s += bq[j] * bk[j];
      *c0 = s;
    }
  }
}

// --- p = nf @ Wqk + bqk ; qb = nf . wqbk + c0 --- (64-row tiles, 256 thr)
__global__ __launch_bounds__(256) void k_p(
    const float* __restrict__ nf, const float* __restrict__ Wqk,
    const float* __restrict__ bqk, const float* __restrict__ wqbk,
    const float* __restrict__ c0p,
    float* __restrict__ p, float* __restrict__ qb) {
  __shared__ float a_lds[64 * DD];
  __shared__ float wb_lds[DD];
  int t = threadIdx.x;
  long row0 = (long)blockIdx.x * 64;
  for (int it = 0; it < 8; it++) {
    int idx = (it * 256 + t) * 4;
    long r = row0 + idx / DD;
    float4 v = {0.f, 0.f, 0.f, 0.f};
    if (r < NN) v = *(const float4*)(nf + r * DD + (idx % DD));
    *(float4*)(a_lds + idx) = v;
  }
  if (t < DD) wb_lds[t] = wqbk[t];
  __syncthreads();
  int cg = t % 32, rg = t / 32;
  int col0 = cg * 4, r0 = rg * 8;
  float acc[8][4]; float qacc[8];
  for (int r = 0; r < 8; r++) { qacc[r] = 0.f; for (int c = 0; c < 4; c++) acc[r][c] = 0.f; }
  for (int k = 0; k < DD; k++) {
    float4 b4 = *(const float4*)(Wqk + k * DD + col0);
    float wbk = wb_lds[k];
    for (int r = 0; r < 8; r++) {
      float a = a_lds[(r0 + r) * DD + k];
      acc[r][0] += a * b4.x; acc[r][1] += a * b4.y;
      acc[r][2] += a * b4.z; acc[r][3] += a * b4.w;
      qacc[r] += a * wbk;
    }
  }
  float4 bq4 = *(const float4*)(bqk + col0);
  float c0v = *c0p;
  for (int r = 0; r < 8; r++) {
    long row = row0 + r0 + r;
    if (row < NN) {
      float4 o;
      o.x = acc[r][0] + bq4.x; o.y = acc[r][1] + bq4.y;
      o.z = acc[r][2] + bq4.z; o.w = acc[r][3] + bq4.w;
      *(float4*)(p + row * DD + col0) = o;
      if (cg == 0) qb[row] = qacc[r] + c0v;
    }
  }
}

// --- pass1 over edges: sim/argmax, attn, ex, seg stats --- (64 edges/block, 4 thr/edge)
__global__ __launch_bounds__(256) void k_edge1(
    const float* __restrict__ tf, const int* __restrict__ ei,
    const float* __restrict__ ce, const float* __restrict__ p,
    const float* __restrict__ qb,
    float* __restrict__ denom, int* __restrict__ cnt_seg,
    int* __restrict__ node_cnt, int* __restrict__ hist,
    float* __restrict__ exv, int* __restrict__ assign) {
  __shared__ float ce_lds[NC * DD];
  __shared__ int lhist[NC];
  int t = threadIdx.x;
  if (t < NC) lhist[t] = 0;
  *(float4*)(ce_lds + t * 4) = *(const float4*)(ce + t * 4);  // 256*4 = 1024 = 8*128
  __syncthreads();

  int el = t >> 2, j = t & 3;
  long e = (long)blockIdx.x * 64 + el;
  const float* trow = tf + e * DD;
  float4 tv[8];
  for (int i = 0; i < 8; i++) tv[i] = *(const float4*)(trow + i * 16 + j * 4);
  int src = ei[e];

  // sim partials -> 4-lane reduce -> argmax (first-max tie-break like jnp.argmax)
  float sims[NC];
  for (int c = 0; c < NC; c++) {
    const float* cr = ce_lds + c * DD;
    float s = 0.f;
    for (int i = 0; i < 8; i++) {
      float4 cv = *(const float4*)(cr + i * 16 + j * 4);
      s += tv[i].x * cv.x + tv[i].y * cv.y + tv[i].z * cv.z + tv[i].w * cv.w;
    }
    sims[c] = s;
  }
  for (int c = 0; c < NC; c++) {
    sims[c] += __shfl_xor(sims[c], 1);
    sims[c] += __shfl_xor(sims[c], 2);
  }
  float best = sims[0]; int bc = 0;
  for (int c = 1; c < NC; c++) if (sims[c] > best) { best = sims[c]; bc = c; }

  // attn = (t . p[src] + qb[src]) * SCALE
  const float* prow = p + (long)src * DD;
  float a = 0.f;
  for (int i = 0; i < 8; i++) {
    float4 pv = *(const float4*)(prow + i * 16 + j * 4);
    a += tv[i].x * pv.x + tv[i].y * pv.y + tv[i].z * pv.z + tv[i].w * pv.w;
  }
  a += __shfl_xor(a, 1);
  a += __shfl_xor(a, 2);
  float attn = (a + qb[src]) * SCALEF;
  float ex = expf(attn);

  if (j == 0) {
    exv[e] = ex;
    assign[e] = bc;
    int seg = bc * NN + src;
    atomicAdd(&denom[seg], ex);
    atomicAdd(&cnt_seg[seg], 1);
    atomicAdd(&node_cnt[src], 1);
    atomicAdd(&lhist[bc], 1);
  }
  __syncthreads();
  if (t < NC) atomicAdd(&hist[t], lhist[t]);
}

// --- prefix scan of node_cnt (3 kernels) + inv_nne ---
__global__ __launch_bounds__(256) void k_scan1(const int* __restrict__ node_cnt,
                                               int* __restrict__ partial) {
  int i = blockIdx.x * 256 + threadIdx.x;
  int v = (i < NN) ? node_cnt[i] : 0;
  for (int o = 1; o < 64; o <<= 1) v += __shfl_xor(v, o);
  __shared__ int wsum[4];
  if ((threadIdx.x & 63) == 0) wsum[threadIdx.x >> 6] = v;
  __syncthreads();
  if (threadIdx.x == 0) partial[blockIdx.x] = wsum[0] + wsum[1] + wsum[2] + wsum[3];
}

__global__ __launch_bounds__(256) void k_scan2(int* __restrict__ partial,
                                               const int* __restrict__ hist,
                                               float* __restrict__ inv_nne) {
  __shared__ int s[256];
  int t = threadIdx.x;
  int v = (t < 196) ? partial[t] : 0;
  s[t] = v;
  __syncthreads();
  for (int o = 1; o < 256; o <<= 1) {
    int add = (t >= o) ? s[t - o] : 0;
    __syncthreads();
    s[t] += add;
    __syncthreads();
  }
  if (t < 196) partial[t] = s[t] - v;  // exclusive
  if (t == 0) {
    int nne = 0;
    for (int c = 0; c < NC; c++) nne += (hist[c] > 0) ? 1 : 0;
    *inv_nne = 1.0f / (float)(nne > 0 ? nne : 1);
  }
}

__global__ __launch_bounds__(256) void k_scan3(const int* __restrict__ node_cnt,
                                               const int* __restrict__ partial,
                                               int* __restrict__ node_off) {
  __shared__ int s[256];
  int t = threadIdx.x;
  int i = blockIdx.x * 256 + t;
  int v = (i < NN) ? node_cnt[i] : 0;
  s[t] = v;
  __syncthreads();
  for (int o = 1; o < 256; o <<= 1) {
    int add = (t >= o) ? s[t - o] : 0;
    __syncthreads();
    s[t] += add;
    __syncthreads();
  }
  if (i < NN) node_off[i] = partial[blockIdx.x] + s[t] - v;
}

// --- counting-sort scatter of edge ids by src ---
__global__ __launch_bounds__(256) void k_scatter(const int* __restrict__ ei,
                                                 const int* __restrict__ node_off,
                                                 int* __restrict__ fill,
                                                 int* __restrict__ sorted) {
  long e = (long)blockIdx.x * 256 + threadIdx.x;
  if (e < NE) {
    int s = ei[e];
    int pos = node_off[s] + atomicAdd(&fill[s], 1);
    sorted[pos] = (int)e;
  }
}

// --- pass2: gather per node, agg[n] = sum scale_e * t_e, sw[n] = sum scale_e ---
// one wave per node; no atomics.
__global__ __launch_bounds__(256) void k_edge2(
    const float* __restrict__ tf, const int* __restrict__ sorted,
    const int* __restrict__ node_off, const int* __restrict__ node_cnt,
    const int* __restrict__ assign, const float* __restrict__ exv,
    const float* __restrict__ denom, const int* __restrict__ cnt_seg,
    float* __restrict__ agg, float* __restrict__ sw) {
  int wave = threadIdx.x >> 6, lane = threadIdx.x & 63;
  int n = blockIdx.x * 4 + wave;
  int off = node_off[n], cnt = node_cnt[n];
  float a0 = 0.f, a1 = 0.f, swa = 0.f;
  for (int base = 0; base < cnt; base += 64) {
    int m = cnt - base; if (m > 64) m = 64;
    int e_l = 0; float s_l = 0.f;
    if (lane < m) {
      e_l = sorted[off + base + lane];
      int c = assign[e_l];
      int seg = c * NN + n;
      s_l = exv[e_l] / (denom[seg] * (float)cnt_seg[seg]);
    }
    for (int ii = 0; ii < m; ii++) {
      int e = __shfl(e_l, ii);
      float s = __shfl(s_l, ii);
      float2 tv = *(const float2*)(tf + (long)e * DD + lane * 2);
      a0 += s * tv.x; a1 += s * tv.y; swa += s;
    }
  }
  float2 o; o.x = a0; o.y = a1;
  *(float2*)(agg + (long)n * DD + lane * 2) = o;
  if (lane == 0) sw[n] = swa;
}

// --- out = relu((agg @ Wvo + sw*bvo) * inv_nne + bo) ---
__global__ __launch_bounds__(256) void k_out(
    const float* __restrict__ agg, const float* __restrict__ Wvo,
    const float* __restrict__ bvo, const float* __restrict__ sw,
    const float* __restrict__ bo, const float* __restrict__ inv_nne,
    float* __restrict__ out) {
  __shared__ float a_lds[64 * DD];
  __shared__ float sw_lds[64];
  int t = threadIdx.x;
  long row0 = (long)blockIdx.x * 64;
  for (int it = 0; it < 8; it++) {
    int idx = (it * 256 + t) * 4;
    long r = row0 + idx / DD;
    float4 v = {0.f, 0.f, 0.f, 0.f};
    if (r < NN) v = *(const float4*)(agg + r * DD + (idx % DD));
    *(float4*)(a_lds + idx) = v;
  }
  if (t < 64) {
    long r = row0 + t;
    sw_lds[t] = (r < NN) ? sw[r] : 0.f;
  }
  __syncthreads();
  int cg = t % 32, rg = t / 32;
  int col0 = cg * 4, r0 = rg * 8;
  float acc[8][4];
  for (int r = 0; r < 8; r++) for (int c = 0; c < 4; c++) acc[r][c] = 0.f;
  for (int k = 0; k < DD; k++) {
    float4 b4 = *(const float4*)(Wvo + k * DD + col0);
    for (int r = 0; r < 8; r++) {
      float a = a_lds[(r0 + r) * DD + k];
      acc[r][0] += a * b4.x; acc[r][1] += a * b4.y;
      acc[r][2] += a * b4.z; acc[r][3] += a * b4.w;
    }
  }
  float4 bv4 = *(const float4*)(bvo + col0);
  float4 bo4 = *(const float4*)(bo + col0);
  float inv = *inv_nne;
  for (int r = 0; r < 8; r++) {
    long row = row0 + r0 + r;
    if (row < NN) {
      float s = sw_lds[r0 + r];
      float4 o;
      o.x = fmaxf((acc[r][0] + s * bv4.x) * inv + bo4.x, 0.f);
      o.y = fmaxf((acc[r][1] + s * bv4.y) * inv + bo4.y, 0.f);
      o.z = fmaxf((acc[r][2] + s * bv4.z) * inv + bo4.z, 0.f);
      o.w = fmaxf((acc[r][3] + s * bv4.w) * inv + bo4.w, 0.f);
      *(float4*)(out + row * DD + col0) = o;
    }
  }
}

extern "C" void kernel_launch(void* const* d_in, const int* in_sizes, int n_in,
                              void* d_out, int out_size, void* d_ws, size_t ws_size,
                              hipStream_t stream) {
  const float* nf = (const float*)d_in[0];
  const float* tf = (const float*)d_in[1];
  // d_in[2] = context_feat: unused by the reference
  const int*   ei = (const int*)d_in[3];   // row 0 = src
  const float* Wq = (const float*)d_in[4];
  const float* bq = (const float*)d_in[5];
  const float* Wk = (const float*)d_in[6];
  const float* bk = (const float*)d_in[7];
  const float* Wv = (const float*)d_in[8];
  const float* bv = (const float*)d_in[9];
  const float* ce = (const float*)d_in[10];
  const float* Wo = (const float*)d_in[11];
  const float* bo = (const float*)d_in[12];
  float* out = (float*)d_out;

  float* ws  = (float*)d_ws;
  float* denom    = ws + OFF_DENOM;
  int*   cnt_seg  = (int*)(ws + OFF_CNTSEG);
  int*   node_cnt = (int*)(ws + OFF_NODECNT);
  int*   fill     = (int*)(ws + OFF_FILL);
  int*   hist     = (int*)(ws + OFF_HIST);
  int*   node_off = (int*)(ws + OFF_NODEOFF);
  int*   partial  = (int*)(ws + OFF_PARTIAL);
  float* inv_nne  = ws + OFF_INVNNE;
  float* c0       = ws + OFF_C0;
  float* bqk      = ws + OFF_BQK;
  float* bvo      = ws + OFF_BVO;
  float* wqbk     = ws + OFF_WQBK;
  float* Wqk      = ws + OFF_WQK;
  float* Wvo      = ws + OFF_WVO;
  float* qb       = ws + OFF_QB;
  float* exv      = ws + OFF_EX;
  int*   assign   = (int*)(ws + OFF_ASSIGN);
  int*   sorted   = (int*)(ws + OFF_SORTED);
  float* sw       = ws + OFF_SW;
  float* p        = ws + OFF_P;     // [N,128]
  float* agg      = ws + OFF_P;     // aliased: p dead after k_edge1, agg lives after

  hipMemsetAsync(d_ws, 0, (size_t)ZERO_ELEMS * 4, stream);

  k_pre<<<129, 128, 0, stream>>>(Wq, bq, Wk, bk, Wv, bv, Wo, Wqk, bqk, Wvo, bvo, wqbk, c0);
  k_p<<<(NN + 63) / 64, 256, 0, stream>>>(nf, Wqk, bqk, wqbk, c0, p, qb);
  k_edge1<<<NE / 64, 256, 0, stream>>>(tf, ei, ce, p, qb, denom, cnt_seg, node_cnt,
                                       hist, exv, assign);
  k_scan1<<<196, 256, 0, stream>>>(node_cnt, partial);
  k_scan2<<<1, 256, 0, stream>>>(partial, hist, inv_nne);
  k_scan3<<<196, 256, 0, stream>>>(node_cnt, partial, node_off);
  k_scatter<<<(NE + 255) / 256, 256, 0, stream>>>(ei, node_off, fill, sorted);
  k_edge2<<<NN / 4, 256, 0, stream>>>(tf, sorted, node_off, node_cnt, assign, exv,
                                      denom, cnt_seg, agg, sw);
  k_out<<<(NN + 63) / 64, 256, 0, stream>>>(agg, Wvo, bvo, sw, bo, inv_nne, out);
}